// Round 7
// baseline (139.621 us; speedup 1.0000x reference)
//
#include <hip/hip_runtime.h>
#include <hip/hip_bf16.h>

// Problem constants (setup_inputs): B=2, N=16384, M=1024, IN=OUT=256
#define NPTS    32768
#define K_DIM   256
#define O_DIM   256
#define M_ATOMS 1024

typedef __attribute__((ext_vector_type(8))) short short8;
typedef __attribute__((ext_vector_type(4))) float f32x4;

// RNE split v = hi + lo (both bf16).
__device__ __forceinline__ void split1(float v, short* h, short* l) {
  unsigned short hu = __bfloat16_as_ushort(__float2bfloat16(v));
  *h = (short)hu;
  float r = v - __uint_as_float((unsigned)hu << 16);
  *l = (short)__bfloat16_as_ushort(__float2bfloat16(r));
}

__device__ __forceinline__ void cvt8(const f32x4 f0, const f32x4 f1,
                                     short8* h, short8* l) {
#pragma unroll
  for (int j = 0; j < 4; ++j) {
    short hh, ll;
    split1(f0[j], &hh, &ll);
    (*h)[j] = hh; (*l)[j] = ll;
    split1(f1[j], &hh, &ll);
    (*h)[j + 4] = hh; (*l)[j + 4] = ll;
  }
}

// async global->LDS, 16B/lane. LDS dest must be WAVE-UNIFORM (HW adds lane*16);
// global src carries the per-lane offset.
__device__ __forceinline__ void async16(void* l, const void* g) {
  __builtin_amdgcn_global_load_lds(
      (const __attribute__((address_space(1))) void*)g,
      (__attribute__((address_space(3))) void*)l, 16, 0, 0);
}

// Kernel 0: W -> bf16 hi/lo, MFMA-fragment-major [kc8][ct16][lane64][e8].
// col = ct*16 + (lane&15), k = kc*32 + (lane>>4)*8 + e  (verified R1-R6).
__global__ __launch_bounds__(256) void wprep_kernel(const float* __restrict__ W,
                                                    unsigned short* __restrict__ whF,
                                                    unsigned short* __restrict__ wlF) {
  int t = blockIdx.x * 256 + threadIdx.x;   // 0..8191
  int lane = t & 63;
  int ct = (t >> 6) & 15;
  int kc = t >> 10;
  int col = ct * 16 + (lane & 15);
  int k0 = kc * 32 + (lane >> 4) * 8;
  const float* src = W + (size_t)col * K_DIM + k0;
  f32x4 f0 = *(const f32x4*)(src);
  f32x4 f1 = *(const f32x4*)(src + 4);
  short8 h, l;
  cvt8(f0, f1, &h, &l);
  *(short8*)(whF + (size_t)t * 8) = h;
  *(short8*)(wlF + (size_t)t * 8) = l;
}

// Fused GEMM + omega + sin.
// 2048 blocks x 128 threads (2 waves). Block: 32 points x 128 cols (col-half).
// 8 blocks/CU -> 16 waves/CU = 4 waves/SIMD. B chunk (BK=32, this col-half,
// hi+lo = 16KB) single-buffered; stage latency covered by other blocks.
__global__ __launch_bounds__(128, 4) void fused_kernel(
    const float* __restrict__ x, const float* __restrict__ qc,
    const float* __restrict__ atoms,
    const unsigned short* __restrict__ whF, const unsigned short* __restrict__ wlF,
    const float* __restrict__ bias,
    const float* __restrict__ fw1, const float* __restrict__ fb1,
    const float* __restrict__ fw2, const float* __restrict__ fb2,
    float* __restrict__ out) {
  __shared__ char lds[16640];               // B chunk 16KB (hi@0, lo@8K) / atoms; red@16384
  const int lane = threadIdx.x & 63;
  const int w = threadIdx.x >> 6;           // wave 0,1
  const int lrow = lane & 15;
  const int lk = lane >> 4;

  // XCD swizzle: physical p -> logical l so the (ch=0, ch=1) pair of each
  // point-group lands on ONE XCD (x rows fetched once from HBM per group).
  const int p = blockIdx.x;
  const int l = (p >> 3) + (p & 7) * 256;   // bijective on [0,2048)
  const int u = l >> 1;                     // point-group 0..1023
  const int ch = l & 1;                     // col half: cols [ch*128, ch*128+128)
  const int pbase = u * 32;

  const char* whB = (const char*)whF + ch * 8192;   // cts [ch*8, ch*8+8) per kc
  const char* wlB = (const char*)wlF + ch * 8192;

  // ---- stage chunk kc=0 ----
#pragma unroll
  for (int r = 0; r < 4; ++r) {
    async16(lds + r * 2048 + w * 1024,
            whB + r * 2048 + w * 1024 + lane * 16);
    async16(lds + 8192 + r * 2048 + w * 1024,
            wlB + r * 2048 + w * 1024 + lane * 16);
  }

  // A row pointers (2 row-tiles of 16 points)
  const float* xr0 = x + (size_t)(pbase + lrow) * K_DIM + lk * 8;
  const float* xr1 = xr0 + 16 * K_DIM;

  // raw A for kc=0
  f32x4 c00 = *(const f32x4*)(xr0), c01 = *(const f32x4*)(xr0 + 4);
  f32x4 c10 = *(const f32x4*)(xr1), c11 = *(const f32x4*)(xr1 + 4);

  f32x4 acc[2][8];
#pragma unroll
  for (int t = 0; t < 2; ++t)
#pragma unroll
    for (int ct = 0; ct < 8; ++ct) acc[t][ct] = (f32x4){0.f, 0.f, 0.f, 0.f};

#pragma unroll 1
  for (int kc = 0; kc < 8; ++kc) {
    // convert raw(kc) -> fragments (VALU; overlaps in-flight stage)
    short8 ahi0, alo0, ahi1, alo1;
    cvt8(c00, c01, &ahi0, &alo0);
    cvt8(c10, c11, &ahi1, &alo1);
    __syncthreads();                        // stage kc visible (drains vmcnt)

    if (kc < 7) {                           // issue raw A(kc+1) early
      const float* p0 = xr0 + (kc + 1) * 32;
      const float* p1 = xr1 + (kc + 1) * 32;
      c00 = *(const f32x4*)(p0); c01 = *(const f32x4*)(p0 + 4);
      c10 = *(const f32x4*)(p1); c11 = *(const f32x4*)(p1 + 4);
    }

    // hi(B) passes: each acc written twice, dep distance = 8 MFMAs
#pragma unroll
    for (int g = 0; g < 2; ++g) {
      const char* bp = lds + g * 4096 + lane * 16;
      short8 b0 = *(const short8*)(bp);
      short8 b1 = *(const short8*)(bp + 1024);
      short8 b2 = *(const short8*)(bp + 2048);
      short8 b3 = *(const short8*)(bp + 3072);
      const int c0 = g * 4;
      acc[0][c0+0] = __builtin_amdgcn_mfma_f32_16x16x32_bf16(ahi0, b0, acc[0][c0+0], 0, 0, 0);
      acc[0][c0+1] = __builtin_amdgcn_mfma_f32_16x16x32_bf16(ahi0, b1, acc[0][c0+1], 0, 0, 0);
      acc[0][c0+2] = __builtin_amdgcn_mfma_f32_16x16x32_bf16(ahi0, b2, acc[0][c0+2], 0, 0, 0);
      acc[0][c0+3] = __builtin_amdgcn_mfma_f32_16x16x32_bf16(ahi0, b3, acc[0][c0+3], 0, 0, 0);
      acc[1][c0+0] = __builtin_amdgcn_mfma_f32_16x16x32_bf16(ahi1, b0, acc[1][c0+0], 0, 0, 0);
      acc[1][c0+1] = __builtin_amdgcn_mfma_f32_16x16x32_bf16(ahi1, b1, acc[1][c0+1], 0, 0, 0);
      acc[1][c0+2] = __builtin_amdgcn_mfma_f32_16x16x32_bf16(ahi1, b2, acc[1][c0+2], 0, 0, 0);
      acc[1][c0+3] = __builtin_amdgcn_mfma_f32_16x16x32_bf16(ahi1, b3, acc[1][c0+3], 0, 0, 0);
      acc[0][c0+0] = __builtin_amdgcn_mfma_f32_16x16x32_bf16(alo0, b0, acc[0][c0+0], 0, 0, 0);
      acc[0][c0+1] = __builtin_amdgcn_mfma_f32_16x16x32_bf16(alo0, b1, acc[0][c0+1], 0, 0, 0);
      acc[0][c0+2] = __builtin_amdgcn_mfma_f32_16x16x32_bf16(alo0, b2, acc[0][c0+2], 0, 0, 0);
      acc[0][c0+3] = __builtin_amdgcn_mfma_f32_16x16x32_bf16(alo0, b3, acc[0][c0+3], 0, 0, 0);
      acc[1][c0+0] = __builtin_amdgcn_mfma_f32_16x16x32_bf16(alo1, b0, acc[1][c0+0], 0, 0, 0);
      acc[1][c0+1] = __builtin_amdgcn_mfma_f32_16x16x32_bf16(alo1, b1, acc[1][c0+1], 0, 0, 0);
      acc[1][c0+2] = __builtin_amdgcn_mfma_f32_16x16x32_bf16(alo1, b2, acc[1][c0+2], 0, 0, 0);
      acc[1][c0+3] = __builtin_amdgcn_mfma_f32_16x16x32_bf16(alo1, b3, acc[1][c0+3], 0, 0, 0);
    }
    // lo(B) passes: ahi only (3-product split)
#pragma unroll
    for (int g = 0; g < 2; ++g) {
      const char* bp = lds + 8192 + g * 4096 + lane * 16;
      short8 b0 = *(const short8*)(bp);
      short8 b1 = *(const short8*)(bp + 1024);
      short8 b2 = *(const short8*)(bp + 2048);
      short8 b3 = *(const short8*)(bp + 3072);
      const int c0 = g * 4;
      acc[0][c0+0] = __builtin_amdgcn_mfma_f32_16x16x32_bf16(ahi0, b0, acc[0][c0+0], 0, 0, 0);
      acc[0][c0+1] = __builtin_amdgcn_mfma_f32_16x16x32_bf16(ahi0, b1, acc[0][c0+1], 0, 0, 0);
      acc[0][c0+2] = __builtin_amdgcn_mfma_f32_16x16x32_bf16(ahi0, b2, acc[0][c0+2], 0, 0, 0);
      acc[0][c0+3] = __builtin_amdgcn_mfma_f32_16x16x32_bf16(ahi0, b3, acc[0][c0+3], 0, 0, 0);
      acc[1][c0+0] = __builtin_amdgcn_mfma_f32_16x16x32_bf16(ahi1, b0, acc[1][c0+0], 0, 0, 0);
      acc[1][c0+1] = __builtin_amdgcn_mfma_f32_16x16x32_bf16(ahi1, b1, acc[1][c0+1], 0, 0, 0);
      acc[1][c0+2] = __builtin_amdgcn_mfma_f32_16x16x32_bf16(ahi1, b2, acc[1][c0+2], 0, 0, 0);
      acc[1][c0+3] = __builtin_amdgcn_mfma_f32_16x16x32_bf16(ahi1, b3, acc[1][c0+3], 0, 0, 0);
    }
    __syncthreads();                        // all reads of buffer done
    if (kc < 7) {                           // restage for kc+1
      const char* gh = whB + (kc + 1) * 16384;
      const char* gl = wlB + (kc + 1) * 16384;
#pragma unroll
      for (int r = 0; r < 4; ++r) {
        async16(lds + r * 2048 + w * 1024,
                gh + r * 2048 + w * 1024 + lane * 16);
        async16(lds + 8192 + r * 2048 + w * 1024,
                gl + r * 2048 + w * 1024 + lane * 16);
      }
    }
  }

  // ---- omega epilogue: atoms (x,y,z,|a|^2) into the 16KB buffer ----
  const int batch = pbase >> 14;            // 32 | 16384, no straddle
  const float* A = atoms + (size_t)batch * M_ATOMS * 3;
  f32x4* at4 = (f32x4*)lds;
  {
    const int t = threadIdx.x;              // 8 atoms per thread
    const f32x4* ap = (const f32x4*)(A + t * 24);
    f32x4 a0 = ap[0], a1 = ap[1], a2 = ap[2], a3 = ap[3], a4 = ap[4], a5 = ap[5];
    f32x4* d = at4 + t * 8;
    d[0] = (f32x4){a0[0], a0[1], a0[2], a0[0]*a0[0] + a0[1]*a0[1] + a0[2]*a0[2]};
    d[1] = (f32x4){a0[3], a1[0], a1[1], a0[3]*a0[3] + a1[0]*a1[0] + a1[1]*a1[1]};
    d[2] = (f32x4){a1[2], a1[3], a2[0], a1[2]*a1[2] + a1[3]*a1[3] + a2[0]*a2[0]};
    d[3] = (f32x4){a2[1], a2[2], a2[3], a2[1]*a2[1] + a2[2]*a2[2] + a2[3]*a2[3]};
    d[4] = (f32x4){a3[0], a3[1], a3[2], a3[0]*a3[0] + a3[1]*a3[1] + a3[2]*a3[2]};
    d[5] = (f32x4){a3[3], a4[0], a4[1], a3[3]*a3[3] + a4[0]*a4[0] + a4[1]*a4[1]};
    d[6] = (f32x4){a4[2], a4[3], a5[0], a4[2]*a4[2] + a4[3]*a4[3] + a5[0]*a5[0]};
    d[7] = (f32x4){a5[1], a5[2], a5[3], a5[1]*a5[1] + a5[2]*a5[2] + a5[3]*a5[3]};
  }
  __syncthreads();

  // min-dist: wave w handles atoms [w*512, w*512+512), 2 lanes/pt
  const int pp = lane & 31;
  const int pt = pbase + pp;
  const float qx = qc[(size_t)pt * 3 + 0];
  const float qy = qc[(size_t)pt * 3 + 1];
  const float qz = qc[(size_t)pt * 3 + 2];
  float m0 = 3.0e38f, m1 = 3.0e38f, m2 = 3.0e38f, m3 = 3.0e38f;
  const int i0 = w * 512 + (lane >> 5) * 256;
  for (int i = i0; i < i0 + 256; i += 4) {
    f32x4 v0 = at4[i + 0], v1 = at4[i + 1], v2 = at4[i + 2], v3 = at4[i + 3];
    float d;
    d = v0[0] * qx; d = __fmaf_rn(v0[1], qy, d); d = __fmaf_rn(v0[2], qz, d);
    m0 = fminf(m0, __fmaf_rn(d, -2.0f, v0[3]));
    d = v1[0] * qx; d = __fmaf_rn(v1[1], qy, d); d = __fmaf_rn(v1[2], qz, d);
    m1 = fminf(m1, __fmaf_rn(d, -2.0f, v1[3]));
    d = v2[0] * qx; d = __fmaf_rn(v2[1], qy, d); d = __fmaf_rn(v2[2], qz, d);
    m2 = fminf(m2, __fmaf_rn(d, -2.0f, v2[3]));
    d = v3[0] * qx; d = __fmaf_rn(v3[1], qy, d); d = __fmaf_rn(v3[2], qz, d);
    m3 = fminf(m3, __fmaf_rn(d, -2.0f, v3[3]));
  }
  float md = fminf(fminf(m0, m1), fminf(m2, m3));
  md = fminf(md, __shfl_xor(md, 32));       // combine the wave's two sub-segments
  // exchange partial min with the other wave
  float* red = (float*)(lds + 16384);
  if (lane < 32) red[w * 32 + lane] = md;
  __syncthreads();
  md = fminf(md, red[(w ^ 1) * 32 + pp]);
  md += qx * qx + qy * qy + qz * qz;        // |q-a|^2 = |q|^2 - 2 q.a + |a|^2
  float mind = sqrtf(fmaxf(md, 1.0e-4f));   // sqrt/max monotone -> commute with min

  float facc = fb2[0];
#pragma unroll
  for (int j = 0; j < 16; ++j) {
    float z = fw1[j * 3 + 0] * qx + fw1[j * 3 + 1] * qy + fw1[j * 3 + 2] * qz + fb1[j];
    // softplus via fast exp/log: max(z,0) + log(1 + e^-|z|)
    facc += fw2[j] * (fmaxf(z, 0.0f) + __logf(1.0f + __expf(-fabsf(z))));
  }
  float ls = fminf(fmaxf(facc, 0.0f), 5.0f); // fmaxf(NaN,0)=0 == nan_to_num(clip)
  float omega_l = 30.0f * (1.0f + ls * __expf(-mind));

  // acc row r of tile t is point t*16 + lk*4 + j -> omega from lane (idx < 32)
  float om[2][4];
#pragma unroll
  for (int t = 0; t < 2; ++t)
#pragma unroll
    for (int j = 0; j < 4; ++j)
      om[t][j] = __shfl(omega_l, t * 16 + lk * 4 + j);

  // ---- store: out[pt, col] = sin(omega * (acc + bias)) ----
#pragma unroll
  for (int ct = 0; ct < 8; ++ct) {
    float bv = bias[ch * 128 + ct * 16 + lrow];
#pragma unroll
    for (int t = 0; t < 2; ++t) {
#pragma unroll
      for (int j = 0; j < 4; ++j) {
        float pre = acc[t][ct][j] + bv;
        out[(size_t)(pbase + t * 16 + lk * 4 + j) * O_DIM + ch * 128 + ct * 16 + lrow] =
            __sinf(om[t][j] * pre);
      }
    }
  }
}

extern "C" void kernel_launch(void* const* d_in, const int* in_sizes, int n_in,
                              void* d_out, int out_size, void* d_ws, size_t ws_size,
                              hipStream_t stream) {
  (void)in_sizes; (void)n_in; (void)out_size; (void)ws_size;
  const float* x     = (const float*)d_in[0];
  const float* qc    = (const float*)d_in[1];
  const float* atoms = (const float*)d_in[2];
  const float* W     = (const float*)d_in[3];
  const float* b     = (const float*)d_in[4];
  const float* fw1   = (const float*)d_in[5];
  const float* fb1   = (const float*)d_in[6];
  const float* fw2   = (const float*)d_in[7];
  const float* fb2   = (const float*)d_in[8];
  float* out = (float*)d_out;

  // workspace: whF[65536] u16 (128 KB) | wlF[65536] u16 (128 KB)
  unsigned short* whF = (unsigned short*)d_ws;
  unsigned short* wlF = whF + 65536;

  wprep_kernel<<<32, 256, 0, stream>>>(W, whF, wlF);
  fused_kernel<<<2048, 128, 0, stream>>>(x, qc, atoms, whF, wlF, b,
                                         fw1, fb1, fw2, fb2, out);
}

// Round 8
// 121.255 us; speedup vs baseline: 1.1515x; 1.1515x over previous
//
#include <hip/hip_runtime.h>
#include <hip/hip_bf16.h>

// Problem constants (setup_inputs): B=2, N=16384, M=1024, IN=OUT=256
#define NPTS    32768
#define K_DIM   256
#define O_DIM   256
#define M_ATOMS 1024

typedef __attribute__((ext_vector_type(8))) short short8;
typedef __attribute__((ext_vector_type(4))) float f32x4;

// RNE split v = hi + lo (both bf16).
__device__ __forceinline__ void split1(float v, short* h, short* l) {
  unsigned short hu = __bfloat16_as_ushort(__float2bfloat16(v));
  *h = (short)hu;
  float r = v - __uint_as_float((unsigned)hu << 16);
  *l = (short)__bfloat16_as_ushort(__float2bfloat16(r));
}

__device__ __forceinline__ void cvt8(const f32x4 f0, const f32x4 f1,
                                     short8* h, short8* l) {
#pragma unroll
  for (int j = 0; j < 4; ++j) {
    short hh, ll;
    split1(f0[j], &hh, &ll);
    (*h)[j] = hh; (*l)[j] = ll;
    split1(f1[j], &hh, &ll);
    (*h)[j + 4] = hh; (*l)[j + 4] = ll;
  }
}

// Kernel 0: W -> bf16 hi/lo, MFMA-fragment-major [kc8][ct16][lane64][e8].
// col = ct*16 + (lane&15), k = kc*32 + (lane>>4)*8 + e  (verified R1-R7).
__global__ __launch_bounds__(256) void wprep_kernel(const float* __restrict__ W,
                                                    unsigned short* __restrict__ whF,
                                                    unsigned short* __restrict__ wlF) {
  int t = blockIdx.x * 256 + threadIdx.x;   // 0..8191
  int lane = t & 63;
  int ct = (t >> 6) & 15;
  int kc = t >> 10;
  int col = ct * 16 + (lane & 15);
  int k0 = kc * 32 + (lane >> 4) * 8;
  const float* src = W + (size_t)col * K_DIM + k0;
  f32x4 f0 = *(const f32x4*)(src);
  f32x4 f1 = *(const f32x4*)(src + 4);
  short8 h, l;
  cvt8(f0, f1, &h, &l);
  *(short8*)(whF + (size_t)t * 8) = h;
  *(short8*)(wlF + (size_t)t * 8) = l;
}

// Fused omega + GEMM + sin. 512 blocks x 256 threads (4 waves).
// Block: 64 points x 256 cols. Wave w: all 64 points x cols [w*64, w*64+64).
// B read DIRECTLY from global (L2-resident, fragment-major -> 1KB coalesced
// wave-loads) into a register double-buffer. NO LDS, NO barriers in the
// K-loop. LDS only for atoms/omega, computed in the PROLOGUE (its VALU time
// hides the B(0)/A(0) prefetch latency).
__global__ __launch_bounds__(256, 2) void fused_kernel(
    const float* __restrict__ x, const float* __restrict__ qc,
    const float* __restrict__ atoms,
    const unsigned short* __restrict__ whF, const unsigned short* __restrict__ wlF,
    const float* __restrict__ bias,
    const float* __restrict__ fw1, const float* __restrict__ fb1,
    const float* __restrict__ fw2, const float* __restrict__ fb2,
    float* __restrict__ out) {
  __shared__ f32x4 at4[M_ATOMS];            // (x,y,z,|a|^2), 16 KB
  __shared__ float red[4][64];
  __shared__ float omg[64];

  const int tid = threadIdx.x;
  const int lane = tid & 63;
  const int w = tid >> 6;                   // wave = col-group
  const int lrow = lane & 15;
  const int lk = lane >> 4;
  const int pbase = blockIdx.x * 64;

  // ---- issue B(kc=0) + A(kc=0) prefetch (latency hidden under omega) ----
  // short8-unit index for (kc,ct): (kc*16 + w*4 + ct)*64 + lane
  const short8* BH = (const short8*)whF + (size_t)(w * 4) * 64 + lane;
  const short8* BL = (const short8*)wlF + (size_t)(w * 4) * 64 + lane;
  short8 bh[4], bl[4], nh[4], nl[4];
#pragma unroll
  for (int ct = 0; ct < 4; ++ct) {
    bh[ct] = BH[ct * 64];
    bl[ct] = BL[ct * 64];
  }
  const float* xr = x + (size_t)(pbase + lrow) * K_DIM + lk * 8;
  f32x4 r0[4], r1[4];
#pragma unroll
  for (int t = 0; t < 4; ++t) {
    r0[t] = *(const f32x4*)(xr + t * 16 * K_DIM);
    r1[t] = *(const f32x4*)(xr + t * 16 * K_DIM + 4);
  }

  // ---- omega prologue ----
  const int batch = pbase >> 14;            // 64 | 16384, no straddle
  const float* A = atoms + (size_t)batch * M_ATOMS * 3;
#pragma unroll
  for (int j = 0; j < 4; ++j) {             // lane-consecutive writes: conflict-free
    int i = tid + j * 256;
    const float* ap = A + (size_t)i * 3;
    float ax = ap[0], ay = ap[1], az = ap[2];
    at4[i] = (f32x4){ax, ay, az, ax * ax + ay * ay + az * az};
  }
  __syncthreads();                          // also drains the B/A prefetch (harmless)

  const int pt = pbase + lane;              // each wave covers all 64 points
  const float qx = qc[(size_t)pt * 3 + 0];
  const float qy = qc[(size_t)pt * 3 + 1];
  const float qz = qc[(size_t)pt * 3 + 2];
  {
    float m0 = 3.0e38f, m1 = 3.0e38f, m2 = 3.0e38f, m3 = 3.0e38f;
    const int i0 = w * 256;                 // wave w scans atoms [w*256, w*256+256)
    for (int i = i0; i < i0 + 256; i += 4) {
      f32x4 v0 = at4[i + 0], v1 = at4[i + 1], v2 = at4[i + 2], v3 = at4[i + 3];
      float d;
      d = v0[0] * qx; d = __fmaf_rn(v0[1], qy, d); d = __fmaf_rn(v0[2], qz, d);
      m0 = fminf(m0, __fmaf_rn(d, -2.0f, v0[3]));
      d = v1[0] * qx; d = __fmaf_rn(v1[1], qy, d); d = __fmaf_rn(v1[2], qz, d);
      m1 = fminf(m1, __fmaf_rn(d, -2.0f, v1[3]));
      d = v2[0] * qx; d = __fmaf_rn(v2[1], qy, d); d = __fmaf_rn(v2[2], qz, d);
      m2 = fminf(m2, __fmaf_rn(d, -2.0f, v2[3]));
      d = v3[0] * qx; d = __fmaf_rn(v3[1], qy, d); d = __fmaf_rn(v3[2], qz, d);
      m3 = fminf(m3, __fmaf_rn(d, -2.0f, v3[3]));
    }
    red[w][lane] = fminf(fminf(m0, m1), fminf(m2, m3));
  }
  __syncthreads();
  if (w == 0) {                             // wave 0 finishes omega for all 64 pts
    float md = fminf(fminf(red[0][lane], red[1][lane]),
                     fminf(red[2][lane], red[3][lane]));
    md += qx * qx + qy * qy + qz * qz;      // |q-a|^2 = |q|^2 - 2 q.a + |a|^2
    float mind = sqrtf(fmaxf(md, 1.0e-4f)); // sqrt/max monotone -> commute with min
    float facc = fb2[0];
#pragma unroll
    for (int j = 0; j < 16; ++j) {
      float z = fw1[j * 3 + 0] * qx + fw1[j * 3 + 1] * qy + fw1[j * 3 + 2] * qz + fb1[j];
      facc += fw2[j] * (fmaxf(z, 0.0f) + __logf(1.0f + __expf(-fabsf(z)))); // softplus
    }
    float ls = fminf(fmaxf(facc, 0.0f), 5.0f); // fmaxf(NaN,0)=0 == nan_to_num(clip)
    omg[lane] = 30.0f * (1.0f + ls * __expf(-mind));
  }
  __syncthreads();                          // omg final; no further barriers needed

  // ---- GEMM: barrier-free, register double-buffered B from L2 ----
  short8 ahi[4], alo[4];
#pragma unroll
  for (int t = 0; t < 4; ++t) cvt8(r0[t], r1[t], &ahi[t], &alo[t]);

  f32x4 acc[4][4];
#pragma unroll
  for (int t = 0; t < 4; ++t)
#pragma unroll
    for (int ct = 0; ct < 4; ++ct) acc[t][ct] = (f32x4){0.f, 0.f, 0.f, 0.f};

#pragma unroll 2
  for (int kc = 0; kc < 8; ++kc) {
    if (kc < 7) {                           // issue next-kc loads before the MFMA burst
#pragma unroll
      for (int ct = 0; ct < 4; ++ct) {
        nh[ct] = BH[(kc + 1) * 1024 + ct * 64];
        nl[ct] = BL[(kc + 1) * 1024 + ct * 64];
      }
#pragma unroll
      for (int t = 0; t < 4; ++t) {
        r0[t] = *(const f32x4*)(xr + t * 16 * K_DIM + (kc + 1) * 32);
        r1[t] = *(const f32x4*)(xr + t * 16 * K_DIM + (kc + 1) * 32 + 4);
      }
    }
    // 48 MFMA: hi*hi, lo*hi, hi*lo; each acc touched 3x at distance 16
#pragma unroll
    for (int ct = 0; ct < 4; ++ct)
#pragma unroll
      for (int t = 0; t < 4; ++t)
        acc[t][ct] = __builtin_amdgcn_mfma_f32_16x16x32_bf16(ahi[t], bh[ct], acc[t][ct], 0, 0, 0);
#pragma unroll
    for (int ct = 0; ct < 4; ++ct)
#pragma unroll
      for (int t = 0; t < 4; ++t)
        acc[t][ct] = __builtin_amdgcn_mfma_f32_16x16x32_bf16(alo[t], bh[ct], acc[t][ct], 0, 0, 0);
#pragma unroll
    for (int ct = 0; ct < 4; ++ct)
#pragma unroll
      for (int t = 0; t < 4; ++t)
        acc[t][ct] = __builtin_amdgcn_mfma_f32_16x16x32_bf16(ahi[t], bl[ct], acc[t][ct], 0, 0, 0);
    if (kc < 7) {                           // convert + rotate (renamed by unroll 2)
#pragma unroll
      for (int t = 0; t < 4; ++t) cvt8(r0[t], r1[t], &ahi[t], &alo[t]);
#pragma unroll
      for (int ct = 0; ct < 4; ++ct) { bh[ct] = nh[ct]; bl[ct] = nl[ct]; }
    }
  }

  // ---- store: out[pt, col] = sin(omega * (acc + bias)) ----
#pragma unroll
  for (int ct = 0; ct < 4; ++ct) {
    float bv = bias[w * 64 + ct * 16 + lrow];
#pragma unroll
    for (int t = 0; t < 4; ++t) {
#pragma unroll
      for (int j = 0; j < 4; ++j) {
        float om = omg[t * 16 + lk * 4 + j];        // LDS broadcast
        float pre = acc[t][ct][j] + bv;
        out[(size_t)(pbase + t * 16 + lk * 4 + j) * O_DIM + w * 64 + ct * 16 + lrow] =
            __sinf(om * pre);
      }
    }
  }
}

extern "C" void kernel_launch(void* const* d_in, const int* in_sizes, int n_in,
                              void* d_out, int out_size, void* d_ws, size_t ws_size,
                              hipStream_t stream) {
  (void)in_sizes; (void)n_in; (void)out_size; (void)ws_size;
  const float* x     = (const float*)d_in[0];
  const float* qc    = (const float*)d_in[1];
  const float* atoms = (const float*)d_in[2];
  const float* W     = (const float*)d_in[3];
  const float* b     = (const float*)d_in[4];
  const float* fw1   = (const float*)d_in[5];
  const float* fb1   = (const float*)d_in[6];
  const float* fw2   = (const float*)d_in[7];
  const float* fb2   = (const float*)d_in[8];
  float* out = (float*)d_out;

  // workspace: whF[65536] u16 (128 KB) | wlF[65536] u16 (128 KB)
  unsigned short* whF = (unsigned short*)d_ws;
  unsigned short* wlF = whF + 65536;

  wprep_kernel<<<32, 256, 0, stream>>>(W, whF, wlF);
  fused_kernel<<<512, 256, 0, stream>>>(x, qc, atoms, whF, wlF, b,
                                        fw1, fb1, fw2, fb2, out);
}